// Round 9
// baseline (27.450 us; speedup 1.0000x reference)
//
#include <hip/hip_runtime.h>
#include <math.h>

#define N_GAUSS 2048
#define IMG_H 256
#define IMG_W 256
#define NPIX (IMG_H * IMG_W)
#define EPS 1e-4f

#define TILE 8
#define TILES_X (IMG_W / TILE)             // 32
#define NTILES (TILES_X * (IMG_H / TILE))  // 1024
#define SEG 512                            // gaussians per wave-segment
#define SEGCAP 128                         // staged candidates per segment (8x margin)
// Half-diagonal of the 8x8 pixel-center extent: 3.5*sqrt(2)/256 = 0.01933495
#define D_HALF 0.019336f                   // strictly above the exact value

// Strict-< sorted-insert ladder; lowest index wins ties (top_k stable order).
#define LADDER(T, G)                                                     \
    if ((T) < v7) {                                                      \
        const bool c0 = (T) < v0, c1 = (T) < v1, c2 = (T) < v2;          \
        const bool c3 = (T) < v3, c4 = (T) < v4, c5 = (T) < v5;          \
        const bool c6 = (T) < v6;                                        \
        v7 = c6 ? v6 : (T);            i7 = c6 ? i6 : (G);               \
        v6 = c6 ? (c5 ? v5 : (T)) : v6; i6 = c6 ? (c5 ? i5 : (G)) : i6;  \
        v5 = c5 ? (c4 ? v4 : (T)) : v5; i5 = c5 ? (c4 ? i4 : (G)) : i5;  \
        v4 = c4 ? (c3 ? v3 : (T)) : v4; i4 = c4 ? (c3 ? i3 : (G)) : i4;  \
        v3 = c3 ? (c2 ? v2 : (T)) : v3; i3 = c3 ? (c2 ? i2 : (G)) : i3;  \
        v2 = c2 ? (c1 ? v1 : (T)) : v2; i2 = c2 ? (c1 ? i1 : (G)) : i2;  \
        v1 = c1 ? (c0 ? v0 : (T)) : v1; i1 = c1 ? (c0 ? i0 : (G)) : i1;  \
        v0 = c0 ? (T) : v0;            i0 = c0 ? (G) : i0;               \
    }

// Compare-exchange on constant-indexed array elems (registers after unroll).
#define CE(a, i, j)                                   \
    { float lo_ = fminf(a[i], a[j]);                  \
      float hi_ = fmaxf(a[i], a[j]);                  \
      a[i] = lo_; a[j] = hi_; }

// Batcher odd-even merge sort network for 8 (19 comparators) -> ascending.
#define SORT8(a)                                      \
    CE(a,0,1) CE(a,2,3) CE(a,4,5) CE(a,6,7)           \
    CE(a,0,2) CE(a,1,3) CE(a,4,6) CE(a,5,7)           \
    CE(a,1,2) CE(a,5,6)                               \
    CE(a,0,4) CE(a,1,5) CE(a,2,6) CE(a,3,7)           \
    CE(a,2,4) CE(a,3,5)                               \
    CE(a,1,2) CE(a,3,4) CE(a,5,6)

// A := sorted 8 smallest of (A ∪ B); A,B ascending. Selection-only (exact).
#define MERGE8(A, B)                                  \
    { float t_[8];                                    \
      t_[0] = fminf(A[0], B[7]); t_[1] = fminf(A[1], B[6]); \
      t_[2] = fminf(A[2], B[5]); t_[3] = fminf(A[3], B[4]); \
      t_[4] = fminf(A[4], B[3]); t_[5] = fminf(A[5], B[2]); \
      t_[6] = fminf(A[6], B[1]); t_[7] = fminf(A[7], B[0]); \
      CE(t_,0,4) CE(t_,1,5) CE(t_,2,6) CE(t_,3,7)     \
      CE(t_,0,2) CE(t_,1,3) CE(t_,4,6) CE(t_,5,7)     \
      CE(t_,0,1) CE(t_,2,3) CE(t_,4,5) CE(t_,6,7)     \
      A[0]=t_[0]; A[1]=t_[1]; A[2]=t_[2]; A[3]=t_[3]; \
      A[4]=t_[4]; A[5]=t_[5]; A[6]=t_[6]; A[7]=t_[7]; }

// In-wave exact top-8 reduce (verbatim from passing R6-R8 kernels).
__device__ __forceinline__ void top8_butterfly(float (&cur)[8]) {
#pragma unroll
    for (int m = 1; m < 64; m <<= 1) {
        float oth[8];
#pragma unroll
        for (int k = 0; k < 8; ++k) oth[k] = __shfl_xor(cur[k], m, 64);
        float t_[8];
#pragma unroll
        for (int k = 0; k < 8; ++k) t_[k] = fminf(cur[k], oth[7 - k]);
        CE(t_,0,4) CE(t_,1,5) CE(t_,2,6) CE(t_,3,7)
        CE(t_,0,2) CE(t_,1,3) CE(t_,4,6) CE(t_,5,7)
        CE(t_,0,1) CE(t_,2,3) CE(t_,4,5) CE(t_,6,7)
#pragma unroll
        for (int k = 0; k < 8; ++k) cur[k] = t_[k];
    }
}

// Per-gaussian precompute: folded screen coefficients + exact trig for the
// bit-exact phase. (float)cos((double)r) is bit-identical to the R2-R8 path.
__global__ void prep_kernel(const float* __restrict__ xy,
                            const float* __restrict__ scale,
                            const float* __restrict__ rot,
                            float4* __restrict__ gA,
                            float4* __restrict__ gB,
                            float4* __restrict__ gC) {
    int g = blockIdx.x * blockDim.x + threadIdx.x;
    if (g >= N_GAUSS) return;
    float x  = xy[2 * g + 0];
    float y  = xy[2 * g + 1];
    float sx = scale[2 * g + 0];
    float sy = scale[2 * g + 1];
    double r = (double)rot[g];
    float c = (float)cos(r);
    float s = (float)sin(r);
    gA[g] = make_float4(x, y, c * sx, s * sx);                    // x,y,m00,m01
    gB[g] = make_float4(-s * sy, c * sy, fmaxf(sx, sy) * D_HALF, 0.f); // m10,m11,margin
    gC[g] = make_float4(c, s, sx, sy);                            // exact params
}

// Fused per-tile kernel: folded fp32 screen + exact bound + ordered
// compaction with LDS staging + bit-exact per-pixel top-8 + blend.
__launch_bounds__(256)
__global__ void fused_kernel(const float* __restrict__ xy,
                             const float4* __restrict__ gA,
                             const float4* __restrict__ gB,
                             const float4* __restrict__ gC,
                             const float* __restrict__ feat,
                             float* __restrict__ out) {
    __shared__ float rlo[N_GAUSS];            // 8 KB: r(center)-m per gaussian
    __shared__ float wlist[4][8];             // per-wave sorted top-8 of rp
    __shared__ float s_cut;
    __shared__ unsigned short qidx[N_GAUSS];  // 4 KB: per-segment candidate ids
    __shared__ int qcnt[4];
    __shared__ float4 cps[4 * SEGCAP];        // 8 KB: staged x,y,cos,sin
    __shared__ float2 csc[4 * SEGCAP];        // 4 KB: staged sx,sy
    __shared__ float          lt[4][8][64];   // 8 KB merge buf
    __shared__ unsigned short li[4][8][64];   // 4 KB

    const int tid  = threadIdx.x;
    const int lane = tid & 63;
    const int w    = tid >> 6;
    const int tile = blockIdx.x;

    // ---------------- Phase A: folded fp32 screen vs tile center -----------
    // r = ||diag(sx,sy) R (p-mu)|| via precomputed M = diag*R; coefficient
    // rounding error <= ~3e-5 absolute on r, absorbed by the 0.01 cut slack.
    const float cx = (float)((tile & (TILES_X - 1)) * TILE + 4) * (1.0f / IMG_W);
    const float cy = (float)((tile / TILES_X) * TILE + 4) * (1.0f / IMG_H);
    float cur[8];
#pragma unroll
    for (int r = 0; r < N_GAUSS / 256; ++r) {     // 8 iterations
        int g = r * 256 + tid;
        float4 a = gA[g];
        float4 b = gB[g];
        float dx = cx - a.x;
        float dy = cy - a.y;
        float lx = dx * a.z + dy * a.w;
        float ly = dx * b.x + dy * b.y;
        float rr = sqrtf(lx * lx + ly * ly);
        rlo[g]  = rr - b.z;
        cur[r]  = rr + b.z;
    }
    SORT8(cur)                                    // ascending, all 8 real

    // ---------------- Phase B: exact global 8th-smallest bound -------------
    top8_butterfly(cur);                          // per-wave exact top-8
    if (lane == 0) {
#pragma unroll
        for (int k = 0; k < 8; ++k) wlist[w][k] = cur[k];
    }
    __syncthreads();

    if (tid == 0) {
        float A[8], B[8], C2[8], D2[8];
#pragma unroll
        for (int k = 0; k < 8; ++k) {
            A[k]  = wlist[0][k];
            B[k]  = wlist[1][k];
            C2[k] = wlist[2][k];
            D2[k] = wlist[3][k];
        }
        MERGE8(A, B)
        MERGE8(C2, D2)
        MERGE8(A, C2)
        float cut = A[7];
        s_cut = cut + 0.01f + 1e-4f * cut;  // slack >> all error budgets
    }
    __syncthreads();
    const float cut = s_cut;

    // ---------------- Phase C: ordered compaction + exact staging ----------
    // Wave w compacts its 512-gaussian segment (ascending index); keeping
    // lanes stage the exact params (from gC, bit-identical trig) into LDS.
    {
        const int segbase = w * SEG;
        unsigned base = 0;
        for (int s2 = 0; s2 < SEG / 64; ++s2) {   // 8 rounds
            int g = segbase + s2 * 64 + lane;
            bool keep = rlo[g] <= cut;
            unsigned long long mask = __ballot(keep);
            if (keep) {
                unsigned pos = base + (unsigned)__popcll(mask & ((1ull << lane) - 1ull));
                qidx[segbase + pos] = (unsigned short)g;
                if (pos < SEGCAP) {
                    float4 a = gA[g];   // x,y in .x,.y
                    float4 e = gC[g];   // c,s,sx,sy
                    cps[w * SEGCAP + pos] = make_float4(a.x, a.y, e.x, e.y);
                    csc[w * SEGCAP + pos] = make_float2(e.z, e.w);
                }
            }
            base += (unsigned)__popcll(mask);
        }
        if (lane == 0) qcnt[w] = (int)base;
    }
    __syncthreads();

    // ---------------- Phase D: bit-exact top-8 over own segment ------------
    const int pxi = (tile & (TILES_X - 1)) * TILE + (lane & 7);
    const int pyi = (tile / TILES_X) * TILE + (lane >> 3);
    const int p   = pyi * IMG_W + pxi;
    const float px = (pxi + 0.5f) * (1.0f / IMG_W);
    const float py = (pyi + 0.5f) * (1.0f / IMG_H);

    float v0 = INFINITY, v1 = INFINITY, v2 = INFINITY, v3 = INFINITY;
    float v4 = INFINITY, v5 = INFINITY, v6 = INFINITY, v7 = INFINITY;
    int   i0 = 0, i1 = 0, i2 = 0, i3 = 0, i4 = 0, i5 = 0, i6 = 0, i7 = 0;

#define PROC_EXACT(AX, AY, AC, AS, BX, BY, G)                            \
    {                                                                    \
        float dx = __fsub_rn(px, (AX));                                  \
        float dy = __fsub_rn(py, (AY));                                  \
        float lx = __fadd_rn(__fmul_rn(dx, (AC)), __fmul_rn(dy, (AS)));  \
        float ly = __fadd_rn(__fmul_rn(-dx, (AS)), __fmul_rn(dy, (AC))); \
        float aa = __fmul_rn(lx, (BX));                                  \
        float bb = __fmul_rn(ly, (BY));                                  \
        float t2 = __fadd_rn(__fmul_rn(aa, aa), __fmul_rn(bb, bb));      \
        LADDER(t2, (G))                                                  \
    }

    {
        const int segbase = w * SEG;
        const int cnt  = qcnt[w];
        const int jcap = cnt < SEGCAP ? cnt : SEGCAP;
        for (int j = 0; j < jcap; ++j) {
            float4 a4 = cps[w * SEGCAP + j];   // uniform addr -> LDS broadcast
            float2 b2 = csc[w * SEGCAP + j];
            int    g  = (int)qidx[segbase + j];
            PROC_EXACT(a4.x, a4.y, a4.z, a4.w, b2.x, b2.y, g)
        }
        // Overflow path (cnt > SEGCAP): never taken for this input (8x
        // margin), kept for provable correctness; bit-identical values.
        for (int j = SEGCAP; j < cnt; ++j) {
            int    g  = (int)qidx[segbase + j];
            float4 a  = gA[g];
            float4 e  = gC[g];
            PROC_EXACT(a.x, a.y, e.x, e.y, e.z, e.w, g)
        }
    }
#undef PROC_EXACT

    lt[w][0][lane] = v0; li[w][0][lane] = (unsigned short)i0;
    lt[w][1][lane] = v1; li[w][1][lane] = (unsigned short)i1;
    lt[w][2][lane] = v2; li[w][2][lane] = (unsigned short)i2;
    lt[w][3][lane] = v3; li[w][3][lane] = (unsigned short)i3;
    lt[w][4][lane] = v4; li[w][4][lane] = (unsigned short)i4;
    lt[w][5][lane] = v5; li[w][5][lane] = (unsigned short)i5;
    lt[w][6][lane] = v6; li[w][6][lane] = (unsigned short)i6;
    lt[w][7][lane] = v7; li[w][7][lane] = (unsigned short)i7;
    __syncthreads();

    if (w == 0) {
        v0 = INFINITY; v1 = INFINITY; v2 = INFINITY; v3 = INFINITY;
        v4 = INFINITY; v5 = INFINITY; v6 = INFINITY; v7 = INFINITY;
        i0 = 0; i1 = 0; i2 = 0; i3 = 0; i4 = 0; i5 = 0; i6 = 0; i7 = 0;
        // Ascending wave order == ascending gaussian index -> identical
        // selection/ordering to the single-stream ladder.
        for (int c = 0; c < 4; ++c) {
#pragma unroll
            for (int k = 0; k < 8; ++k) {
                float t2 = lt[c][k][lane];
                int   g  = (int)li[c][k][lane];
                LADDER(t2, g)
            }
        }
        float w0 = expf(-0.5f * v0), w1 = expf(-0.5f * v1);
        float w2 = expf(-0.5f * v2), w3 = expf(-0.5f * v3);
        float w4 = expf(-0.5f * v4), w5 = expf(-0.5f * v5);
        float w6 = expf(-0.5f * v6), w7 = expf(-0.5f * v7);
        float sum = w0 + w1 + w2 + w3 + w4 + w5 + w6 + w7;
        float inv = 1.0f / (sum + EPS);

        float oc0 = 0.f, oc1 = 0.f, oc2 = 0.f;
#define ACC(K)                                                  \
        {                                                       \
            float al = w##K * inv;                              \
            const float* f = feat + 3 * i##K;                   \
            oc0 = fmaf(al, f[0], oc0);                          \
            oc1 = fmaf(al, f[1], oc1);                          \
            oc2 = fmaf(al, f[2], oc2);                          \
        }
        ACC(0) ACC(1) ACC(2) ACC(3) ACC(4) ACC(5) ACC(6) ACC(7)
#undef ACC

        out[p]            = oc0;
        out[p + NPIX]     = oc1;
        out[p + 2 * NPIX] = oc2;
    }
}

extern "C" void kernel_launch(void* const* d_in, const int* in_sizes, int n_in,
                              void* d_out, int out_size, void* d_ws, size_t ws_size,
                              hipStream_t stream) {
    const float* xy    = (const float*)d_in[0];
    const float* scale = (const float*)d_in[1];
    const float* rot   = (const float*)d_in[2];
    const float* feat  = (const float*)d_in[3];
    float* out = (float*)d_out;

    float4* gA = (float4*)d_ws;            // 32 KB
    float4* gB = gA + N_GAUSS;             // 32 KB
    float4* gC = gB + N_GAUSS;             // 32 KB  (total 96 KB of ws)

    prep_kernel<<<N_GAUSS / 256, 256, 0, stream>>>(xy, scale, rot, gA, gB, gC);
    fused_kernel<<<NTILES, 256, 0, stream>>>(xy, gA, gB, gC, feat, out);
}